// Round 2
// baseline (93.082 us; speedup 1.0000x reference)
//
#include <hip/hip_runtime.h>
#include <hip/hip_bf16.h>

typedef __bf16 bf16x8 __attribute__((ext_vector_type(8)));
typedef float f32x4 __attribute__((ext_vector_type(4)));
typedef unsigned short ushort4v __attribute__((ext_vector_type(4)));
typedef unsigned short ushort8v __attribute__((ext_vector_type(8)));

#define B_  16
#define C_  256
#define HW_ 4096
#define E_  8

__device__ inline unsigned short f2bf(float f) {
    unsigned int b = __builtin_bit_cast(unsigned int, f);
    b += 0x7FFFu + ((b >> 16) & 1u);   // RNE (inputs finite)
    return (unsigned short)(b >> 16);
}

// ================= FAST PATH =================

// K1: read X fp32 [b][c][p]; write Xt bf16 [b][p][c]; partial c-sums [b*C+c][32]
__global__ __launch_bounds__(256) void k_prep(const float* __restrict__ in,
                                              unsigned short* __restrict__ Xt,
                                              float* __restrict__ partial) {
    int ptile = blockIdx.x;            // 0..31 -> 128 p each
    int b = blockIdx.y;
    int p0 = ptile * 128;
    __shared__ float Ts[32][132];      // [c_loc][p_loc] fp32
    int t = threadIdx.x;
    const float* Xb = in + (size_t)b * C_ * HW_;

    for (int chunk = 0; chunk < 8; ++chunk) {
        int c0 = chunk * 32;
        float csum[4];
#pragma unroll
        for (int pass = 0; pass < 4; ++pass) {
            int cl = pass * 8 + (t >> 5);               // 0..31
            int pl = (t & 31) * 4;                      // 0..124
            float4 v = *reinterpret_cast<const float4*>(
                Xb + (size_t)(c0 + cl) * HW_ + p0 + pl);
            csum[pass] = v.x + v.y + v.z + v.w;
            *reinterpret_cast<float4*>(&Ts[cl][pl]) = v;
        }
        __syncthreads();
        // transposed bf16 write: thread -> row p, 16 c's
        {
            int pl = t & 127, ch = t >> 7;              // ch in {0,1}
            unsigned short* dst =
                Xt + ((size_t)(b * HW_ + p0 + pl)) * C_ + c0 + ch * 16;
#pragma unroll
            for (int j = 0; j < 2; ++j) {
                ushort8v u;
#pragma unroll
                for (int jj = 0; jj < 8; ++jj)
                    u[jj] = f2bf(Ts[ch * 16 + j * 8 + jj][pl]);
                *reinterpret_cast<ushort8v*>(dst + j * 8) = u;
            }
        }
        // per-c partial sums (reduce 32 lanes sharing a c)
#pragma unroll
        for (int pass = 0; pass < 4; ++pass) {
            float s = csum[pass];
#pragma unroll
            for (int off = 16; off; off >>= 1) s += __shfl_down(s, off, 32);
            if ((t & 31) == 0) {
                int c = c0 + pass * 8 + (t >> 5);
                partial[(size_t)(b * C_ + c) * 32 + ptile] = s;
            }
        }
        __syncthreads();
    }
}

// K2: reduce partials -> pooled (LDS); logits; softmax; top2 gates; biasE
__global__ __launch_bounds__(256) void k_router2(const float* __restrict__ partial,
                                                 const float* __restrict__ Wr,
                                                 const float* __restrict__ br,
                                                 const float* __restrict__ bexp,
                                                 float* __restrict__ gates,
                                                 float* __restrict__ biasE) {
    __shared__ float pl[B_ * C_];     // 16 KB
    __shared__ float wrs[C_ * E_];    // 8 KB
    __shared__ float lgh[B_ * E_][2];
    __shared__ float gs[B_][E_];
    int t = threadIdx.x;
#pragma unroll
    for (int i = 0; i < 16; ++i) {
        int r = t + i * 256;
        const float4* p4 = reinterpret_cast<const float4*>(partial + (size_t)r * 32);
        float s = 0.f;
#pragma unroll
        for (int j = 0; j < 8; ++j) {
            float4 v = p4[j];
            s += v.x + v.y + v.z + v.w;
        }
        pl[r] = s * (1.0f / HW_);
    }
#pragma unroll
    for (int i = 0; i < 2; ++i) {
        int idx = t + i * 256;
        reinterpret_cast<float4*>(wrs)[idx] =
            reinterpret_cast<const float4*>(Wr)[idx];
    }
    __syncthreads();
    {
        int pair = t >> 1, half = t & 1;
        int b = pair >> 3, e = pair & 7;
        float s = 0.f;
        int c0 = half * 128;
        for (int c = c0; c < c0 + 128; ++c) s += pl[b * C_ + c] * wrs[c * E_ + e];
        lgh[pair][half] = s;
    }
    __syncthreads();
    if (t < B_) {
        float w[E_];
        float m = -1e30f;
#pragma unroll
        for (int e = 0; e < E_; ++e) {
            w[e] = lgh[t * E_ + e][0] + lgh[t * E_ + e][1] + br[e];
            m = fmaxf(m, w[e]);
        }
        float sum = 0.f;
#pragma unroll
        for (int e = 0; e < E_; ++e) { w[e] = __expf(w[e] - m); sum += w[e]; }
        float inv = 1.f / sum;
#pragma unroll
        for (int e = 0; e < E_; ++e) w[e] *= inv;
        int i0 = 0;
#pragma unroll
        for (int e = 1; e < E_; ++e) if (w[e] > w[i0]) i0 = e;
        int i1 = -1;
#pragma unroll
        for (int e = 0; e < E_; ++e) {
            if (e == i0) continue;
            if (i1 < 0 || w[e] > w[i1]) i1 = e;
        }
#pragma unroll
        for (int e = 0; e < E_; ++e) {
            float g = (e == i0 || e == i1) ? w[e] : 0.f;
            gs[t][e] = g;
            gates[t * E_ + e] = g;
        }
    }
    __syncthreads();
    {
        int d = t;
        float acc[B_];
#pragma unroll
        for (int b = 0; b < B_; ++b) acc[b] = 0.f;
#pragma unroll
        for (int e = 0; e < E_; ++e) {
            float w = bexp[e * C_ + d];
#pragma unroll
            for (int b = 0; b < B_; ++b) acc[b] += gs[b][e] * w;
        }
#pragma unroll
        for (int b = 0; b < B_; ++b) biasE[b * C_ + d] = acc[b];
    }
}

// K3: W_eff[b][d][c] = sum_e g[b,e] * W_exp[e,d,c]  (bf16)
__global__ __launch_bounds__(256) void k_weff(const float* __restrict__ Wexp,
                                              const float* __restrict__ gates,
                                              unsigned short* __restrict__ Weff) {
    int b = blockIdx.y;
    int dblk = blockIdx.x;
    __shared__ float g[E_];
    int t = threadIdx.x;
    if (t < E_) g[t] = gates[b * E_ + t];
    __syncthreads();
    int dloc = t >> 5, cq = t & 31;
    int d = dblk * 8 + dloc;
#pragma unroll
    for (int half = 0; half < 2; half++) {
        int c = (cq + half * 32) * 4;
        float4 acc = {0.f, 0.f, 0.f, 0.f};
#pragma unroll
        for (int e = 0; e < E_; e++) {
            float ge = g[e];
            if (ge != 0.f) {
                float4 w = *reinterpret_cast<const float4*>(
                    Wexp + ((size_t)(e * C_ + d)) * C_ + c);
                acc.x += ge * w.x; acc.y += ge * w.y;
                acc.z += ge * w.z; acc.w += ge * w.w;
            }
        }
        ushort4v o = { f2bf(acc.x), f2bf(acc.y), f2bf(acc.z), f2bf(acc.w) };
        *reinterpret_cast<ushort4v*>(Weff + ((size_t)(b * C_ + d)) * C_ + c) = o;
    }
}

// K4 fast: out[b] = x[b] + W_eff[b] @ x[b] + biasE[b]
// A=Weff [d][c] bf16, B=Xt [p][c] bf16, both k-contiguous. BK=64.
// Staging via global_load_lds w=16, XOR-swizzled source; swizzled ds_read.
__global__ __launch_bounds__(256) void k_gemm_f(const float* __restrict__ in,
                                                const unsigned short* __restrict__ Weff,
                                                const unsigned short* __restrict__ Xt,
                                                const float* __restrict__ biasE,
                                                float* __restrict__ out) {
    __shared__ unsigned short As[128 * 64];   // linear rows of 64 shorts (128 B)
    __shared__ unsigned short Bs[128 * 64];
    int t = threadIdx.x;
    int n0 = blockIdx.x * 128, m0 = blockIdx.y * 128, b = blockIdx.z;
    const unsigned short* Wb = Weff + (size_t)b * C_ * C_;
    const unsigned short* Xb = Xt + (size_t)b * HW_ * C_;
    int lane = t & 63, wid = t >> 6;
    int wr = wid >> 1, wc = wid & 1;
    int kg = lane >> 4, lr = lane & 15;
    int lrow = lane >> 3, lcd = lane & 7;    // staging: row-in-block, dest chunk

    f32x4 acc[4][4];
#pragma unroll
    for (int i = 0; i < 4; i++)
#pragma unroll
        for (int j = 0; j < 4; j++) acc[i][j] = (f32x4){0.f, 0.f, 0.f, 0.f};

    for (int k0 = 0; k0 < C_; k0 += 64) {
#pragma unroll
        for (int j = 0; j < 4; ++j) {
            int blk = wid * 4 + j;           // 0..15, wave-uniform
            int r = blk * 8 + lrow;          // tile row 0..127
            int cs = lcd ^ (r & 7);          // inverse-swizzled source chunk
            const unsigned short* sa = Wb + (size_t)(m0 + r) * C_ + k0 + cs * 8;
            const unsigned short* sb = Xb + (size_t)(n0 + r) * C_ + k0 + cs * 8;
            __builtin_amdgcn_global_load_lds(
                (const __attribute__((address_space(1))) void*)sa,
                (__attribute__((address_space(3))) void*)(As + blk * 512), 16, 0, 0);
            __builtin_amdgcn_global_load_lds(
                (const __attribute__((address_space(1))) void*)sb,
                (__attribute__((address_space(3))) void*)(Bs + blk * 512), 16, 0, 0);
        }
        __syncthreads();
#pragma unroll
        for (int ks = 0; ks < 2; ++ks) {
            int cc = ks * 4 + kg;
            bf16x8 af[4], bfv[4];
#pragma unroll
            for (int mi = 0; mi < 4; ++mi) {
                int ra = wr * 64 + mi * 16 + lr;
                af[mi] = __builtin_bit_cast(bf16x8,
                    *reinterpret_cast<const ushort8v*>(&As[ra * 64 + (cc ^ (ra & 7)) * 8]));
            }
#pragma unroll
            for (int ni = 0; ni < 4; ++ni) {
                int rb = wc * 64 + ni * 16 + lr;
                bfv[ni] = __builtin_bit_cast(bf16x8,
                    *reinterpret_cast<const ushort8v*>(&Bs[rb * 64 + (cc ^ (rb & 7)) * 8]));
            }
#pragma unroll
            for (int mi = 0; mi < 4; ++mi)
#pragma unroll
                for (int ni = 0; ni < 4; ++ni)
                    acc[mi][ni] = __builtin_amdgcn_mfma_f32_16x16x32_bf16(
                        af[mi], bfv[ni], acc[mi][ni], 0, 0, 0);
        }
        __syncthreads();
    }

    const float* inB = in + (size_t)b * C_ * HW_;
    float* outB = out + (size_t)b * C_ * HW_;
#pragma unroll
    for (int mi = 0; mi < 4; mi++) {
#pragma unroll
        for (int j = 0; j < 4; j++) {
            int row = m0 + wr * 64 + mi * 16 + kg * 4 + j;
            float bias = biasE[b * C_ + row];
            const float* inRow = inB + (size_t)row * HW_;
            float* outRow = outB + (size_t)row * HW_;
#pragma unroll
            for (int ni = 0; ni < 4; ni++) {
                int col = n0 + wc * 64 + ni * 16 + lr;
                outRow[col] = acc[mi][ni][j] + inRow[col] + bias;
            }
        }
    }
}

// ================= FALLBACK (round-1, known-passing) =================

__global__ __launch_bounds__(256) void k_pool(const float* __restrict__ in,
                                              float* __restrict__ pooled) {
    int bc = blockIdx.x;
    const float* p = in + (size_t)bc * HW_;
    int t = threadIdx.x;
    float s = 0.f;
#pragma unroll
    for (int i = 0; i < 4; i++) {
        float4 v = *reinterpret_cast<const float4*>(p + (size_t)(t + i * 256) * 4);
        s += v.x + v.y + v.z + v.w;
    }
#pragma unroll
    for (int off = 32; off; off >>= 1) s += __shfl_down(s, off, 64);
    __shared__ float part[4];
    if ((t & 63) == 0) part[t >> 6] = s;
    __syncthreads();
    if (t == 0) pooled[bc] = (part[0] + part[1] + part[2] + part[3]) * (1.0f / HW_);
}

__global__ __launch_bounds__(256) void k_router(const float* __restrict__ pooled,
                                                const float* __restrict__ Wr,
                                                const float* __restrict__ br,
                                                const float* __restrict__ bexp,
                                                float* __restrict__ gates,
                                                float* __restrict__ biasE) {
    __shared__ float lg[B_][E_];
    __shared__ float gs[B_][E_];
    int t = threadIdx.x;
    if (t < B_ * E_) {
        int b = t >> 3, e = t & 7;
        float s = br[e];
        for (int c = 0; c < C_; c++) s += pooled[b * C_ + c] * Wr[c * E_ + e];
        lg[b][e] = s;
    }
    __syncthreads();
    if (t < B_) {
        float w[E_];
        float m = lg[t][0];
#pragma unroll
        for (int e = 1; e < E_; e++) m = fmaxf(m, lg[t][e]);
        float sum = 0.f;
#pragma unroll
        for (int e = 0; e < E_; e++) { w[e] = __expf(lg[t][e] - m); sum += w[e]; }
        float inv = 1.f / sum;
#pragma unroll
        for (int e = 0; e < E_; e++) w[e] *= inv;
        int i0 = 0;
#pragma unroll
        for (int e = 1; e < E_; e++) if (w[e] > w[i0]) i0 = e;
        int i1 = -1;
#pragma unroll
        for (int e = 0; e < E_; e++) {
            if (e == i0) continue;
            if (i1 < 0 || w[e] > w[i1]) i1 = e;
        }
#pragma unroll
        for (int e = 0; e < E_; e++) {
            float g = (e == i0 || e == i1) ? w[e] : 0.f;
            gs[t][e] = g;
            gates[t * E_ + e] = g;
        }
    }
    __syncthreads();
    int d = t;
    for (int b = 0; b < B_; b++) {
        float s = 0.f;
#pragma unroll
        for (int e = 0; e < E_; e++) s += gs[b][e] * bexp[e * C_ + d];
        biasE[b * C_ + d] = s;
    }
}

#define BKo  32
#define LDAo 40
#define LDBo 36

__global__ __launch_bounds__(256) void k_gemm(const float* __restrict__ in,
                                              const unsigned short* __restrict__ Weff,
                                              const float* __restrict__ biasE,
                                              float* __restrict__ out) {
    __shared__ unsigned short As[128 * LDAo];
    __shared__ unsigned short Bs[128 * LDBo];
    int t = threadIdx.x;
    int n0 = blockIdx.x * 128, m0 = blockIdx.y * 128, b = blockIdx.z;
    const float* inB = in + (size_t)b * C_ * HW_;
    const unsigned short* Wb = Weff + (size_t)b * C_ * C_;
    int lane = t & 63, wid = t >> 6;
    int wr = wid >> 1, wc = wid & 1;
    int kg = lane >> 4, lr = lane & 15;

    f32x4 acc[4][4];
#pragma unroll
    for (int i = 0; i < 4; i++)
#pragma unroll
        for (int j = 0; j < 4; j++) acc[i][j] = (f32x4){0.f, 0.f, 0.f, 0.f};

    for (int k0 = 0; k0 < C_; k0 += BKo) {
#pragma unroll
        for (int i = 0; i < 2; i++) {
            int chunk = t + i * 256;
            int row = chunk >> 2, c8 = chunk & 3;
            ushort8v v = *reinterpret_cast<const ushort8v*>(
                Wb + (size_t)(m0 + row) * C_ + k0 + c8 * 8);
            *reinterpret_cast<ushort8v*>(&As[row * LDAo + c8 * 8]) = v;
        }
        {
            int p = t & 127, ch = t >> 7;
            const float* src = inB + (size_t)k0 * HW_ + n0 + p;
#pragma unroll
            for (int cq = 0; cq < 4; cq++) {
                int c = ch * 16 + cq * 4;
                float x0 = src[(size_t)(c + 0) * HW_];
                float x1 = src[(size_t)(c + 1) * HW_];
                float x2 = src[(size_t)(c + 2) * HW_];
                float x3 = src[(size_t)(c + 3) * HW_];
                ushort4v v = { f2bf(x0), f2bf(x1), f2bf(x2), f2bf(x3) };
                *reinterpret_cast<ushort4v*>(&Bs[p * LDBo + c]) = v;
            }
        }
        __syncthreads();
        bf16x8 af[4], bfr[4];
#pragma unroll
        for (int mi = 0; mi < 4; mi++) {
            int row = wr * 64 + mi * 16 + lr;
            af[mi] = __builtin_bit_cast(bf16x8,
                *reinterpret_cast<const ushort8v*>(&As[row * LDAo + kg * 8]));
        }
#pragma unroll
        for (int ni = 0; ni < 4; ni++) {
            int rowp = wc * 64 + ni * 16 + lr;
            ushort4v lo = *reinterpret_cast<const ushort4v*>(&Bs[rowp * LDBo + kg * 8]);
            ushort4v hi = *reinterpret_cast<const ushort4v*>(&Bs[rowp * LDBo + kg * 8 + 4]);
            ushort8v u = __builtin_shufflevector(lo, hi, 0, 1, 2, 3, 4, 5, 6, 7);
            bfr[ni] = __builtin_bit_cast(bf16x8, u);
        }
#pragma unroll
        for (int mi = 0; mi < 4; mi++)
#pragma unroll
            for (int ni = 0; ni < 4; ni++)
                acc[mi][ni] = __builtin_amdgcn_mfma_f32_16x16x32_bf16(
                    af[mi], bfr[ni], acc[mi][ni], 0, 0, 0);
        __syncthreads();
    }

    float* outB = out + (size_t)b * C_ * HW_;
#pragma unroll
    for (int mi = 0; mi < 4; mi++) {
#pragma unroll
        for (int j = 0; j < 4; j++) {
            int row = m0 + wr * 64 + mi * 16 + kg * 4 + j;
            float bias = biasE[b * C_ + row];
            const float* inRow = inB + (size_t)row * HW_;
            float* outRow = outB + (size_t)row * HW_;
#pragma unroll
            for (int ni = 0; ni < 4; ni++) {
                int col = n0 + wc * 64 + ni * 16 + lr;
                outRow[col] = acc[mi][ni][j] + inRow[col] + bias;
            }
        }
    }
}

extern "C" void kernel_launch(void* const* d_in, const int* in_sizes, int n_in,
                              void* d_out, int out_size, void* d_ws, size_t ws_size,
                              hipStream_t stream) {
    const float* in   = (const float*)d_in[0];
    const float* Wr   = (const float*)d_in[1];
    const float* br   = (const float*)d_in[2];
    const float* Wexp = (const float*)d_in[3];
    const float* bexp = (const float*)d_in[4];
    float* out = (float*)d_out;
    char* ws = (char*)d_ws;

    if (ws_size >= (size_t)0x2400000) {
        float* partial        = (float*)(ws);                    // 512 KB
        float* gates          = (float*)(ws + 0x80000);          // 512 B
        float* biasE          = (float*)(ws + 0x81000);          // 16 KB
        unsigned short* Weff  = (unsigned short*)(ws + 0x90000); // 2 MB
        unsigned short* Xt    = (unsigned short*)(ws + 0x400000);// 32 MB

        hipLaunchKernelGGL(k_prep,    dim3(32, B_), dim3(256), 0, stream, in, Xt, partial);
        hipLaunchKernelGGL(k_router2, dim3(1),      dim3(256), 0, stream,
                           partial, Wr, br, bexp, gates, biasE);
        hipLaunchKernelGGL(k_weff,    dim3(32, B_), dim3(256), 0, stream, Wexp, gates, Weff);
        hipLaunchKernelGGL(k_gemm_f,  dim3(HW_ / 128, C_ / 128, B_), dim3(256), 0, stream,
                           in, Weff, Xt, biasE, out);
    } else {
        float* pooled         = (float*)(ws);
        float* gates          = (float*)(ws + 16 * 1024);
        float* biasE          = (float*)(ws + 20 * 1024);
        unsigned short* Weff  = (unsigned short*)(ws + 64 * 1024);

        hipLaunchKernelGGL(k_pool,   dim3(B_ * C_), dim3(256), 0, stream, in, pooled);
        hipLaunchKernelGGL(k_router, dim3(1),       dim3(256), 0, stream,
                           pooled, Wr, br, bexp, gates, biasE);
        hipLaunchKernelGGL(k_weff,   dim3(32, B_),  dim3(256), 0, stream, Wexp, gates, Weff);
        hipLaunchKernelGGL(k_gemm,   dim3(HW_ / 128, C_ / 128, B_), dim3(256), 0, stream,
                           in, Weff, biasE, out);
    }
}

// Round 3
// 55.244 us; speedup vs baseline: 1.6849x; 1.6849x over previous
//
#include <hip/hip_runtime.h>
#include <hip/hip_bf16.h>

typedef __bf16 bf16x8 __attribute__((ext_vector_type(8)));
typedef float f32x4 __attribute__((ext_vector_type(4)));
typedef unsigned short ushort4v __attribute__((ext_vector_type(4)));
typedef unsigned short ushort8v __attribute__((ext_vector_type(8)));

#define B_  16
#define C_  256
#define HW_ 4096
#define E_  8

__device__ inline unsigned short f2bf(float f) {
    unsigned int b = __builtin_bit_cast(unsigned int, f);
    b += 0x7FFFu + ((b >> 16) & 1u);   // RNE (inputs finite)
    return (unsigned short)(b >> 16);
}

// ---------------- K1: pooled[b][c] = mean_{h,w} inputs[b,c,h,w] ----------------
__global__ __launch_bounds__(256) void k_pool(const float* __restrict__ in,
                                              float* __restrict__ pooled) {
    int bc = blockIdx.x;
    const float* p = in + (size_t)bc * HW_;
    int t = threadIdx.x;
    float s = 0.f;
#pragma unroll
    for (int i = 0; i < 4; i++) {
        float4 v = *reinterpret_cast<const float4*>(p + (size_t)(t + i * 256) * 4);
        s += v.x + v.y + v.z + v.w;
    }
#pragma unroll
    for (int off = 32; off; off >>= 1) s += __shfl_down(s, off, 64);
    __shared__ float part[4];
    if ((t & 63) == 0) part[t >> 6] = s;
    __syncthreads();
    if (t == 0) pooled[bc] = (part[0] + part[1] + part[2] + part[3]) * (1.0f / HW_);
}

// ---------------- K2: router (LDS-parallel) + effective bias -------------------
__global__ __launch_bounds__(256) void k_router3(const float* __restrict__ pooled,
                                                 const float* __restrict__ Wr,
                                                 const float* __restrict__ br,
                                                 const float* __restrict__ bexp,
                                                 float* __restrict__ gates,
                                                 float* __restrict__ biasE) {
    __shared__ float pl[B_ * C_];     // 16 KB
    __shared__ float wrs[C_ * E_];    // 8 KB
    __shared__ float lgh[B_ * E_][2];
    __shared__ float gs[B_][E_];
    int t = threadIdx.x;
#pragma unroll
    for (int i = 0; i < 4; ++i)
        reinterpret_cast<float4*>(pl)[t + i * 256] =
            reinterpret_cast<const float4*>(pooled)[t + i * 256];
#pragma unroll
    for (int i = 0; i < 2; ++i)
        reinterpret_cast<float4*>(wrs)[t + i * 256] =
            reinterpret_cast<const float4*>(Wr)[t + i * 256];
    __syncthreads();
    {
        int pair = t >> 1, half = t & 1;
        int b = pair >> 3, e = pair & 7;
        float s = 0.f;
        int c0 = half * 128;
        for (int c = c0; c < c0 + 128; ++c) s += pl[b * C_ + c] * wrs[c * E_ + e];
        lgh[pair][half] = s;
    }
    __syncthreads();
    if (t < B_) {
        float w[E_];
        float m = -1e30f;
#pragma unroll
        for (int e = 0; e < E_; ++e) {
            w[e] = lgh[t * E_ + e][0] + lgh[t * E_ + e][1] + br[e];
            m = fmaxf(m, w[e]);
        }
        float sum = 0.f;
#pragma unroll
        for (int e = 0; e < E_; ++e) { w[e] = __expf(w[e] - m); sum += w[e]; }
        float inv = 1.f / sum;
#pragma unroll
        for (int e = 0; e < E_; ++e) w[e] *= inv;
        int i0 = 0;
#pragma unroll
        for (int e = 1; e < E_; ++e) if (w[e] > w[i0]) i0 = e;
        int i1 = -1;
#pragma unroll
        for (int e = 0; e < E_; ++e) {
            if (e == i0) continue;
            if (i1 < 0 || w[e] > w[i1]) i1 = e;
        }
#pragma unroll
        for (int e = 0; e < E_; ++e) {
            float g = (e == i0 || e == i1) ? w[e] : 0.f;
            gs[t][e] = g;
            gates[t * E_ + e] = g;
        }
    }
    __syncthreads();
    {
        int d = t;
        float acc[B_];
#pragma unroll
        for (int b = 0; b < B_; ++b) acc[b] = 0.f;
#pragma unroll
        for (int e = 0; e < E_; ++e) {
            float w = bexp[e * C_ + d];
#pragma unroll
            for (int b = 0; b < B_; ++b) acc[b] += gs[b][e] * w;
        }
#pragma unroll
        for (int b = 0; b < B_; ++b) biasE[b * C_ + d] = acc[b];
    }
}

// ---------------- K3: W_eff[b][d][c] = sum_e g[b,e] * W_exp[e,d,c] (bf16) ------
__global__ __launch_bounds__(256) void k_weff(const float* __restrict__ Wexp,
                                              const float* __restrict__ gates,
                                              unsigned short* __restrict__ Weff) {
    int b = blockIdx.y;
    int dblk = blockIdx.x;
    __shared__ float g[E_];
    int t = threadIdx.x;
    if (t < E_) g[t] = gates[b * E_ + t];
    __syncthreads();
    int dloc = t >> 5, cq = t & 31;
    int d = dblk * 8 + dloc;
#pragma unroll
    for (int half = 0; half < 2; half++) {
        int c = (cq + half * 32) * 4;
        float4 acc = {0.f, 0.f, 0.f, 0.f};
#pragma unroll
        for (int e = 0; e < E_; e++) {
            float ge = g[e];
            if (ge != 0.f) {
                float4 w = *reinterpret_cast<const float4*>(
                    Wexp + ((size_t)(e * C_ + d)) * C_ + c);
                acc.x += ge * w.x; acc.y += ge * w.y;
                acc.z += ge * w.z; acc.w += ge * w.w;
            }
        }
        ushort4v o = { f2bf(acc.x), f2bf(acc.y), f2bf(acc.z), f2bf(acc.w) };
        *reinterpret_cast<ushort4v*>(Weff + ((size_t)(b * C_ + d)) * C_ + c) = o;
    }
}

// ---------------- K4: fused  out[b] = x + Weff[b] @ x + biasE[b] ---------------
// Tile: M=256 (full), N=64, full K=256 resident in LDS as Bs[p][c] bf16.
// 8 waves, wave w owns rows [w*32, w*32+32). Identity via acc-init from Bs.
#define TSLD 68   // Ts row stride (floats): 16B-aligned rows, conflict-free

__global__ __launch_bounds__(512, 4) void k_fused(const float* __restrict__ in,
                                                  const unsigned short* __restrict__ Weff,
                                                  const float* __restrict__ biasE,
                                                  float* __restrict__ out) {
    __shared__ unsigned short Bs[64 * 256];   // 32 KB, [p][c] chunk-swizzled
    __shared__ float Ts[64 * TSLD];           // 17 KB transpose staging
    const int t = threadIdx.x;
    const int b = blockIdx.y;
    const int n0 = blockIdx.x * 64;
    const int lane = t & 63, w = t >> 6;
    const int kg = lane >> 4, lr = lane & 15;
    const float* inB = in + (size_t)b * C_ * HW_ + n0;
    const unsigned short* Wb = Weff + (size_t)b * C_ * C_;
    const unsigned short* aptr = Wb + (size_t)(w * 32 + lr) * C_ + kg * 8;

    // early A prefetch for kf=0 (completes under staging)
    bf16x8 a0[2], a1[2];
#pragma unroll
    for (int mi = 0; mi < 2; ++mi)
        a0[mi] = __builtin_bit_cast(bf16x8,
            *reinterpret_cast<const ushort8v*>(aptr + mi * 16 * C_));

    // ---- stage B = x^T bf16 into Bs (4 passes of 64c x 64p) ----
    {
        const int cl = t >> 3;          // 0..63  (source c row)
        const int pq = (t & 7) * 8;     // 0..56  (source p offset)
        const int pr = t & 63;          // transpose-read p
        const int cq = t >> 6;          // 0..7   (c-chunk, wave-uniform)
        for (int pass = 0; pass < 4; ++pass) {
            const float* src = inB + (size_t)(pass * 64 + cl) * HW_ + pq;
            float4 v0 = *reinterpret_cast<const float4*>(src);
            float4 v1 = *reinterpret_cast<const float4*>(src + 4);
            *reinterpret_cast<float4*>(&Ts[cl * TSLD + pq]) = v0;
            *reinterpret_cast<float4*>(&Ts[cl * TSLD + pq + 4]) = v1;
            __syncthreads();
            ushort8v u;
#pragma unroll
            for (int j = 0; j < 8; ++j)
                u[j] = f2bf(Ts[(cq * 8 + j) * TSLD + pr]);
            const int chunk = (pass * 8 + cq) ^ (pr & 7);
            *reinterpret_cast<ushort8v*>(&Bs[pr * 256 + chunk * 8]) = u;
            __syncthreads();
        }
    }

    // ---- acc init: identity (from Bs) + bias ----
    f32x4 acc[2][4];
#pragma unroll
    for (int mi = 0; mi < 2; ++mi) {
#pragma unroll
        for (int j = 0; j < 4; ++j) {
            const int row = w * 32 + mi * 16 + kg * 4 + j;
            const float bias = biasE[b * C_ + row];
#pragma unroll
            for (int ni = 0; ni < 4; ++ni) {
                const int p = ni * 16 + lr;
                unsigned short xv =
                    Bs[p * 256 + (((row >> 3) ^ (p & 7)) * 8) + (row & 7)];
                float xf = __builtin_bit_cast(float, (unsigned int)xv << 16);
                acc[mi][ni][j] = xf + bias;
            }
        }
    }

    // ---- MFMA main: 8 k-frags x (2 mi x 4 ni), A double-buffered in regs ----
#pragma unroll
    for (int kf = 0; kf < 8; kf += 2) {
#pragma unroll
        for (int mi = 0; mi < 2; ++mi)
            a1[mi] = __builtin_bit_cast(bf16x8,
                *reinterpret_cast<const ushort8v*>(aptr + mi * 16 * C_ + (kf + 1) * 32));
        {
            bf16x8 bfv[4];
#pragma unroll
            for (int ni = 0; ni < 4; ++ni) {
                const int p = ni * 16 + lr;
                bfv[ni] = __builtin_bit_cast(bf16x8,
                    *reinterpret_cast<const ushort8v*>(
                        &Bs[p * 256 + (((kf * 4 + kg) ^ (lr & 7)) * 8)]));
            }
#pragma unroll
            for (int mi = 0; mi < 2; ++mi)
#pragma unroll
                for (int ni = 0; ni < 4; ++ni)
                    acc[mi][ni] = __builtin_amdgcn_mfma_f32_16x16x32_bf16(
                        a0[mi], bfv[ni], acc[mi][ni], 0, 0, 0);
        }
        if (kf + 2 < 8) {
#pragma unroll
            for (int mi = 0; mi < 2; ++mi)
                a0[mi] = __builtin_bit_cast(bf16x8,
                    *reinterpret_cast<const ushort8v*>(aptr + mi * 16 * C_ + (kf + 2) * 32));
        }
        {
            bf16x8 bfv[4];
#pragma unroll
            for (int ni = 0; ni < 4; ++ni) {
                const int p = ni * 16 + lr;
                bfv[ni] = __builtin_bit_cast(bf16x8,
                    *reinterpret_cast<const ushort8v*>(
                        &Bs[p * 256 + ((((kf + 1) * 4 + kg) ^ (lr & 7)) * 8)]));
            }
#pragma unroll
            for (int mi = 0; mi < 2; ++mi)
#pragma unroll
                for (int ni = 0; ni < 4; ++ni)
                    acc[mi][ni] = __builtin_amdgcn_mfma_f32_16x16x32_bf16(
                        a1[mi], bfv[ni], acc[mi][ni], 0, 0, 0);
        }
    }

    // ---- store ----
    float* outB = out + (size_t)b * C_ * HW_ + n0;
#pragma unroll
    for (int mi = 0; mi < 2; ++mi) {
#pragma unroll
        for (int j = 0; j < 4; ++j) {
            const int row = w * 32 + mi * 16 + kg * 4 + j;
            float* orow = outB + (size_t)row * HW_;
#pragma unroll
            for (int ni = 0; ni < 4; ++ni)
                orow[ni * 16 + lr] = acc[mi][ni][j];
        }
    }
}

extern "C" void kernel_launch(void* const* d_in, const int* in_sizes, int n_in,
                              void* d_out, int out_size, void* d_ws, size_t ws_size,
                              hipStream_t stream) {
    const float* in   = (const float*)d_in[0];
    const float* Wr   = (const float*)d_in[1];
    const float* br   = (const float*)d_in[2];
    const float* Wexp = (const float*)d_in[3];
    const float* bexp = (const float*)d_in[4];
    float* out = (float*)d_out;
    char* ws = (char*)d_ws;

    float* pooled         = (float*)(ws);                    // 16 KB
    float* gates          = (float*)(ws + 0x10000);          // 512 B
    float* biasE          = (float*)(ws + 0x11000);          // 16 KB
    unsigned short* Weff  = (unsigned short*)(ws + 0x20000); // 2 MB

    hipLaunchKernelGGL(k_pool,    dim3(B_ * C_), dim3(256), 0, stream, in, pooled);
    hipLaunchKernelGGL(k_router3, dim3(1),       dim3(256), 0, stream,
                       pooled, Wr, br, bexp, gates, biasE);
    hipLaunchKernelGGL(k_weff,    dim3(32, B_),  dim3(256), 0, stream, Wexp, gates, Weff);
    hipLaunchKernelGGL(k_fused,   dim3(HW_ / 64, B_), dim3(512), 0, stream,
                       in, Weff, biasE, out);
}